// Round 9
// baseline (351.470 us; speedup 1.0000x reference)
//
#include <hip/hip_runtime.h>

typedef unsigned short u16;
typedef __attribute__((ext_vector_type(4))) float floatx4;
typedef __attribute__((ext_vector_type(4))) unsigned short u16x4;
typedef __attribute__((ext_vector_type(8))) short short8;
typedef __attribute__((ext_vector_type(8))) __bf16 bf16x8;

#define B_SZ 8
#define C_LEN 2048
#define Q_LEN 512
#define D_DIM 1024
#define K4 (4 * D_DIM)

static __device__ __forceinline__ u16 f2bf(float f) {
    union { float f; unsigned int u; } v; v.f = f;
    unsigned int r = v.u + 0x7FFFu + ((v.u >> 16) & 1u);  // round-to-nearest-even
    return (u16)(r >> 16);
}
static __device__ __forceinline__ float bf2f(u16 h) {
    union { unsigned int u; float f; } v; v.u = ((unsigned int)h) << 16;
    return v.f;
}

// async global->LDS, 16B per lane; LDS dest = wave-uniform base + lane*16
static __device__ __forceinline__ void async16(const void* g, void* l) {
    __builtin_amdgcn_global_load_lds(
        (const __attribute__((address_space(1))) unsigned int*)g,
        (__attribute__((address_space(3))) unsigned int*)(unsigned int)(unsigned long long)l,
        16, 0, 0);
}

// ---------- fused prep: precast_c | precast_q | transpose_q | zero q2c ----------
__global__ __launch_bounds__(256) void prep_kernel(
    const float* __restrict__ c, const float* __restrict__ q,
    const float* __restrict__ w_cq, const float* __restrict__ w_c, const float* __restrict__ w_q,
    u16* __restrict__ cbf, u16* __restrict__ qwbf, u16* __restrict__ qT,
    float* __restrict__ rowterm, float* __restrict__ colterm, float* __restrict__ q2c) {
    int blk = blockIdx.x;
    int tid = threadIdx.x;
    if (blk < 4096) {
        // precast_c: cbf = bf16(c); rowterm = c . w_c
        int row = blk * 4 + (tid >> 6);
        int lane = tid & 63;
        const float* src = c + (size_t)row * D_DIM;
        u16* dst = cbf + (size_t)row * D_DIM;
        float s = 0.f;
        #pragma unroll
        for (int j = 0; j < 4; ++j) {
            int idx = j * 256 + lane * 4;
            floatx4 a = *(const floatx4*)(src + idx);
            floatx4 w = *(const floatx4*)(w_c + idx);
            s += a[0]*w[0] + a[1]*w[1] + a[2]*w[2] + a[3]*w[3];
            u16x4 o;
            #pragma unroll
            for (int e = 0; e < 4; ++e) o[e] = f2bf(a[e]);
            *(u16x4*)(dst + idx) = o;
        }
        for (int off = 32; off; off >>= 1) s += __shfl_down(s, off);
        if (lane == 0) rowterm[row] = s;
    } else if (blk < 5120) {
        // precast_q: qwbf = bf16(q .* w_cq); colterm = q . w_q
        int row = (blk - 4096) * 4 + (tid >> 6);
        int lane = tid & 63;
        const float* src = q + (size_t)row * D_DIM;
        u16* dst = qwbf + (size_t)row * D_DIM;
        float s = 0.f;
        #pragma unroll
        for (int j = 0; j < 4; ++j) {
            int idx = j * 256 + lane * 4;
            floatx4 a  = *(const floatx4*)(src + idx);
            floatx4 wc = *(const floatx4*)(w_cq + idx);
            floatx4 wq = *(const floatx4*)(w_q + idx);
            s += a[0]*wq[0] + a[1]*wq[1] + a[2]*wq[2] + a[3]*wq[3];
            u16x4 o;
            #pragma unroll
            for (int e = 0; e < 4; ++e) o[e] = f2bf(a[e] * wc[e]);
            *(u16x4*)(dst + idx) = o;
        }
        for (int off = 32; off; off >>= 1) s += __shfl_down(s, off);
        if (lane == 0) colterm[row] = s;
    } else if (blk < 9216) {
        // transpose_q: qT[b,d,q] = bf16(q[b,q,d])
        __shared__ float tile[32][33];
        int t = blk - 5120;
        int q0 = (t & 15) * 32;
        int d0 = ((t >> 4) & 31) * 32;
        int b = t >> 9;
        int tx = tid & 31, ty = tid >> 5;  // 32 x 8
        const float* qb = q + (size_t)b * Q_LEN * D_DIM;
        #pragma unroll
        for (int j = 0; j < 4; ++j) {
            int row = ty + j * 8;
            tile[row][tx] = qb[(size_t)(q0 + row) * D_DIM + d0 + tx];
        }
        __syncthreads();
        u16* qTb = qT + (size_t)b * D_DIM * Q_LEN;
        #pragma unroll
        for (int j = 0; j < 4; ++j) {
            int row = ty + j * 8;
            qTb[(size_t)(d0 + row) * Q_LEN + q0 + tx] = f2bf(tile[tx][row]);
        }
    } else {
        // zero q2c (8192 floats)
        int i = (blk - 9216) * 256 + tid;
        q2c[i] = 0.0f;
    }
}

// ---------- fused W prep: Wm[b,n,k] = bf16(W1 + W4*q2c); Wbf[n,kk] = bf16(W[n,1024+kk]) ----------
__global__ __launch_bounds__(256) void wmerge_all(const float* __restrict__ W, const float* __restrict__ q2c,
                                                  u16* __restrict__ Wm, u16* __restrict__ Wbf) {
    int n = blockIdx.x;             // 1024 rows
    int k = threadIdx.x * 4;        // 0..1023
    const float* wr = W + (size_t)n * K4;
    floatx4 w1 = *(const floatx4*)(wr + k);
    floatx4 w4 = *(const floatx4*)(wr + 3072 + k);
    #pragma unroll
    for (int p = 0; p < 2; ++p) {
        int kk = p * 1024 + k;
        floatx4 v = *(const floatx4*)(wr + 1024 + kk);
        u16x4 o;
        #pragma unroll
        for (int e = 0; e < 4; ++e) o[e] = f2bf(v[e]);
        *(u16x4*)(Wbf + (size_t)n * 2048 + kk) = o;
    }
    #pragma unroll
    for (int b = 0; b < 8; ++b) {
        floatx4 g = *(const floatx4*)(q2c + (size_t)b * D_DIM + k);
        u16x4 o;
        #pragma unroll
        for (int e = 0; e < 4; ++e) o[e] = f2bf(w1[e] + w4[e] * g[e]);
        *(u16x4*)(Wm + (size_t)b * 1048576 + (size_t)n * 1024 + k) = o;
    }
}

// ---------- unified async bf16 GEMM, C = A @ B^T, 128x128 tile, BK=64, swizzled LDS ----------
// (kept for MODE 0 and MODE 1; MODE 2 uses gemm2_8q below)
template<int MODE>
__global__ __launch_bounds__(256) void gemm_async(
    const u16* __restrict__ A0, const u16* __restrict__ A1, const u16* __restrict__ A2,
    const u16* __restrict__ B0, const u16* __restrict__ B1,
    float* __restrict__ of, u16* __restrict__ ob, const float* __restrict__ bias) {
    constexpr int NSEC = (MODE == 2) ? 3 : 1;
    constexpr int KSEC = (MODE == 1) ? 512 : 1024;
    constexpr int LDO  = (MODE == 0) ? 512 : 1024;
    constexpr int NTILES = (MODE == 0) ? 4 : 8;
    __shared__ u16 As[128 * 64];
    __shared__ u16 Bs[128 * 64];
    const int tid  = threadIdx.x;
    const int lane = tid & 63;
    const int wave = tid >> 6;
    const int lin  = blockIdx.x;
    const int b    = lin & 7;            // XCD pin
    const int rem  = lin >> 3;
    const int n0   = (rem % NTILES) * 128;
    const int m0   = (rem / NTILES) * 128;

    const u16* Aarr[NSEC];
    const u16* Barr[NSEC];
    int lda_[NSEC], ldb_[NSEC];
    if constexpr (MODE == 0) {
        Aarr[0] = A0 + (size_t)b * C_LEN * D_DIM; lda_[0] = 1024;
        Barr[0] = B0 + (size_t)b * Q_LEN * D_DIM; ldb_[0] = 1024;
    } else if constexpr (MODE == 1) {
        Aarr[0] = A0 + (size_t)b * C_LEN * Q_LEN; lda_[0] = 512;
        Barr[0] = B0 + (size_t)b * D_DIM * Q_LEN; ldb_[0] = 512;
    } else {
        Aarr[0] = A0 + (size_t)b * C_LEN * D_DIM;  lda_[0] = 1024;
        Barr[0] = B0 + (size_t)b * D_DIM * D_DIM;  ldb_[0] = 1024;   // Wm (per-batch)
        Aarr[1] = A1 + (size_t)b * C_LEN * 2048;        lda_[1] = 2048;  // CC + 0
        Barr[1] = B1;                                   ldb_[1] = 2048;  // Wbf + 0
        Aarr[2] = A1 + (size_t)b * C_LEN * 2048 + 1024; lda_[2] = 2048;  // CC + 1024
        Barr[2] = B1 + 1024;                            ldb_[2] = 2048;  // Wbf + 1024
    }

    // staging geometry: 16 chunks of 8 rows; wave w stages chunks 4w..4w+3
    const int srow = lane >> 3;                    // 0..7 row-within-chunk
    const int ssc  = ((lane & 7) ^ srow) * 8;      // swizzled source column (u16)

    floatx4 acc[4][4];
    #pragma unroll
    for (int i = 0; i < 4; ++i)
        #pragma unroll
        for (int j = 0; j < 4; ++j)
            acc[i][j] = (floatx4)(0.0f);

    const int wrow = (wave >> 1) * 64;
    const int wcol = (wave & 1) * 64;
    const int quad = lane >> 4;
    const int lrow = lane & 15;
    const int sw7  = lane & 7;                     // row&7 for all reader rows

    #pragma unroll
    for (int sec = 0; sec < NSEC; ++sec) {
        const u16* __restrict__ Ab = Aarr[sec];
        const u16* __restrict__ Bb = Barr[sec];
        const int LA = lda_[sec];
        const int LB = ldb_[sec];
        for (int k0 = 0; k0 < KSEC; k0 += 64) {
            #pragma unroll
            for (int cc = 0; cc < 4; ++cc) {
                int ch = wave * 4 + cc;
                int rr = ch * 8 + srow;
                async16(Ab + (size_t)(m0 + rr) * LA + k0 + ssc, &As[ch * 512]);
            }
            #pragma unroll
            for (int cc = 0; cc < 4; ++cc) {
                int ch = wave * 4 + cc;
                int rr = ch * 8 + srow;
                async16(Bb + (size_t)(n0 + rr) * LB + k0 + ssc, &Bs[ch * 512]);
            }
            __syncthreads();
            #pragma unroll
            for (int h = 0; h < 2; ++h) {
                const int pc = ((h * 4 + quad) ^ sw7) * 8;   // physical column (u16)
                bf16x8 af[4], bfr[4];
                #pragma unroll
                for (int i = 0; i < 4; ++i)
                    af[i] = __builtin_bit_cast(bf16x8, *(const short8*)&As[(wrow + i*16 + lrow) * 64 + pc]);
                #pragma unroll
                for (int j = 0; j < 4; ++j)
                    bfr[j] = __builtin_bit_cast(bf16x8, *(const short8*)&Bs[(wcol + j*16 + lrow) * 64 + pc]);
                #pragma unroll
                for (int i = 0; i < 4; ++i)
                    #pragma unroll
                    for (int j = 0; j < 4; ++j)
                        acc[i][j] = __builtin_amdgcn_mfma_f32_16x16x32_bf16(af[i], bfr[j], acc[i][j], 0, 0, 0);
            }
            __syncthreads();
        }
    }

    // ---- epilogue; C/D layout: col = lane&15, row = quad*4 + reg ----
    float* ofb = nullptr; u16* ccb = nullptr; const u16* cbr = nullptr;
    if (MODE == 0)      ofb = of + (size_t)b * C_LEN * Q_LEN;
    else if (MODE == 1) { ccb = ob + (size_t)b * C_LEN * 2048; cbr = A1 + (size_t)b * C_LEN * D_DIM; }
    else                ofb = of + (size_t)b * C_LEN * D_DIM;
    #pragma unroll
    for (int i = 0; i < 4; ++i) {
        #pragma unroll
        for (int j = 0; j < 4; ++j) {
            #pragma unroll
            for (int e = 0; e < 4; ++e) {
                int gm = m0 + wrow + i * 16 + quad * 4 + e;
                int gn = n0 + wcol + j * 16 + lrow;
                float v = acc[i][j][e];
                if (MODE == 0)      ofb[(size_t)gm * LDO + gn] = v;
                else if (MODE == 1) {
                    u16 p = f2bf(v);
                    float cv = bf2f(cbr[(size_t)gm * 1024 + gn]);
                    ccb[(size_t)gm * 2048 + gn]        = p;
                    ccb[(size_t)gm * 2048 + 1024 + gn] = f2bf(cv * bf2f(p));
                }
                else                ofb[(size_t)gm * LDO + gn] = v + bias[gn];
            }
        }
    }
}

// ---------- 256x256-tile, m201-template 4-phase/quadrant bf16 GEMM (output projection) ----------
// z[b] = cbf[b] @ Wm[b]^T + CC0[b] @ Wbf0^T + CC1[b] @ Wbf1^T + b_l   (K = 3*1024 = 48 tiles of 64)
//
// Round-7 postmortem: coarse read-block->MFMA-block schedules all plateau at ~4880
// cyc/tile; the PROVEN m201 template (same geometry, 1563 TF) uses per-phase
// {reads | stage | BAR | lgkm(0) | 16 MFMA | BAR} with C-QUADRANT phases and
// register operand reuse between consecutive phases. Faithful port:
//   * Per phase, all 8 waves compute one 128x128 C-quadrant (wave sub-tile 64x32).
//     Quadrant order Q00(Ah0,Bh0) -> Q10(Ah1,Bh0: B reused) -> Q11(Ah1,Bh1: A
//     reused) -> Q01(Ah0,Bh1: B reused). Reads/phase: 12/8/4/8.
//   * Progressive half-panel deaths: Bh0 dead @ph2-end, Ah1 @ph3-end, Ah0+Bh1
//     @ph4-end -> stage slots one-per-phase into the freed region:
//       ph1(t): Bh1(t+1)->buf^1 [Bh1(t-1) died ph4(t-1)]
//       ph2(t): Ah0(t+1)->buf^1 [Ah0(t-1) died ph4(t-1)]
//       ph3(t): Bh0(t+2)->buf   [Bh0(t)   died ph2(t)]
//       ph4(t): Ah1(t+2)->buf   [Ah1(t)   died ph3(t)]
//   * Counted vmcnt once per K-tile @ph4-end: VMW(4) leaves only {Bh0(t+2),
//     Ah1(t+2)} in flight; all tile-t+1 halves proven landed (each half staged
//     >= 3 stage-slots before its wait). Tail tt>=46: VMW(0).
//   * Half-panel = 128 rows x 64 k = 2 global_load_lds/wave; proven chunk^(row&7)
//     swizzle (0 bank conflicts, round 3).
#define BAR8() __builtin_amdgcn_s_barrier()
#define VMW(N) do { asm volatile("s_waitcnt vmcnt(" #N ")" ::: "memory"); } while (0)
#define LGK0() do { asm volatile("s_waitcnt lgkmcnt(0)" ::: "memory"); } while (0)
#define LGK8() do { asm volatile("s_waitcnt lgkmcnt(8)" ::: "memory"); } while (0)

// read the 8 A-frags (4 mi x 2 kh) of quadrant row-half QM from buffer CUR
#define RD_A(QM, CUR) do { \
    const u16* ua_ = lds_ + (CUR) * 32768; \
    _Pragma("unroll") \
    for (int mi_ = 0; mi_ < 4; ++mi_) \
      _Pragma("unroll") \
      for (int kh_ = 0; kh_ < 2; ++kh_) \
        afr[mi_*2+kh_] = __builtin_bit_cast(bf16x8, \
            *(const short8*)(ua_ + ((QM)*128 + wr*64 + mi_*16 + lrow) * 64 + pca[kh_])); \
  } while (0)

// read the 4 B-frags (2 ni x 2 kh) of quadrant col-half QN from buffer CUR
#define RD_B(QN, CUR) do { \
    const u16* ub_ = lds_ + (CUR) * 32768 + 16384; \
    _Pragma("unroll") \
    for (int ni_ = 0; ni_ < 2; ++ni_) \
      _Pragma("unroll") \
      for (int kh_ = 0; kh_ < 2; ++kh_) \
        bfr[ni_*2+kh_] = __builtin_bit_cast(bf16x8, \
            *(const short8*)(ub_ + ((QN)*128 + wc*32 + ni_*16 + lrow) * 64 + pca[kh_])); \
  } while (0)

// 16 MFMA into the named quadrant accumulator (static indexing, rule #20)
#define MM16(ACC) do { \
    __builtin_amdgcn_s_setprio(1); \
    _Pragma("unroll") \
    for (int kh_ = 0; kh_ < 2; ++kh_) \
      _Pragma("unroll") \
      for (int mi_ = 0; mi_ < 4; ++mi_) \
        _Pragma("unroll") \
        for (int ni_ = 0; ni_ < 2; ++ni_) \
          ACC[mi_*2+ni_] = __builtin_amdgcn_mfma_f32_16x16x32_bf16( \
              afr[mi_*2+kh_], bfr[ni_*2+kh_], ACC[mi_*2+ni_], 0, 0, 0); \
    __builtin_amdgcn_s_setprio(0); \
  } while (0)

__global__ __launch_bounds__(512, 2) void gemm2_8q(
    const u16* __restrict__ cbf, const u16* __restrict__ CC,
    const u16* __restrict__ Wm, const u16* __restrict__ Wbf,
    float* __restrict__ of, const float* __restrict__ bias) {
    __shared__ __align__(16) u16 lds_[65536];  // [buf2][A|B][row256][col64] = 128 KiB
    const int tid  = threadIdx.x;
    const int lane = tid & 63;
    const int wave = tid >> 6;          // 8 waves: 2 (qrow) x 4 (qcol)
    const int lin  = blockIdx.x;
    const int b    = lin & 7;           // XCD pin: one batch per XCD
    const int rem  = lin >> 3;          // 0..31 -> 8 m-tiles x 4 n-tiles
    const int n0   = (rem & 3) * 256;
    const int m0   = (rem >> 2) * 256;
    const int wr   = wave >> 2;         // 0..1: row-64 within a 128x128 quadrant
    const int wc   = wave & 3;          // 0..3: col-32 within a 128x128 quadrant
    const int quad = lane >> 4;
    const int lrow = lane & 15;
    const int lr7  = lane & 7;          // == row&7 for every fragment-read row
    // physical 16B chunk (u16 offset) for logical k-chunk (KH*4 + quad):
    const int pca[2] = { ((0 + quad) ^ lr7) * 8, ((4 + quad) ^ lr7) * 8 };

    const u16* Acb  = cbf + (size_t)b * (C_LEN * D_DIM);
    const u16* Acc0 = CC  + (size_t)b * (C_LEN * 2048);
    const u16* Acc1 = Acc0 + 1024;
    const u16* Bwm  = Wm  + (size_t)b * (D_DIM * D_DIM);

    // stage one half-panel (ab: 0=A,1=B; hf: 0/1 = rows hf*128..+127) of tile tt
    // into buffer tt&1. Linear LDS dest, inverse-swizzled global source:
    // LDS[row][pchunk] = global[row][pchunk ^ (row&7)]  (8 chunks of 16B per row).
    auto STAGE = [&](int tt, int ab, int hf) {
        const int sec = tt >> 4;                    // 3 K-sections of 16 tiles
        const int kl  = (tt & 15) * 64;             // local k within section
        const u16* base;
        int r0;
        if (ab == 0) { base = (sec == 0) ? Acb : (sec == 1) ? Acc0 : Acc1; r0 = m0; }
        else         { base = (sec == 0) ? Bwm : (sec == 1) ? Wbf  : Wbf + 1024; r0 = n0; }
        r0 += hf * 128;
        const int ld = (sec == 0) ? 1024 : 2048;
        u16* unit = lds_ + (tt & 1) * 32768 + ab * 16384 + hf * 8192;
        #pragma unroll
        for (int l = 0; l < 2; ++l) {
            const int li  = l * 512 + tid;          // 0..1023 -> (row 0..127, chunk)
            const int row = li >> 3;
            const int sc  = (li & 7) ^ (row & 7);   // inverse swizzle on global col
            async16(base + (size_t)(r0 + row) * ld + kl + sc * 8,
                    unit + (size_t)(l * 512 + (tid & ~63)) * 8);
        }
    };

    floatx4 acc0[8], acc1[8], acc2[8], acc3[8];  // Q00, Q10, Q11, Q01
    #pragma unroll
    for (int i = 0; i < 8; ++i) {
        acc0[i] = (floatx4)(0.0f); acc1[i] = (floatx4)(0.0f);
        acc2[i] = (floatx4)(0.0f); acc3[i] = (floatx4)(0.0f);
    }

    // prologue: tile 0 complete + the ph3(-1)/ph4(-1) slots {Bh0(1), Ah1(1)}.
    STAGE(0, 0, 0); STAGE(0, 1, 0); STAGE(0, 0, 1); STAGE(0, 1, 1);
    STAGE(1, 1, 0); STAGE(1, 0, 1);
    VMW(4);                        // tile 0's 4 halves landed; 2 tile-1 halves fly
    BAR8();

    bf16x8 afr[8], bfr[4];
    for (int tt = 0; tt < 48; ++tt) {
        const int cur = tt & 1;
        // ---- ph1: Q00 (Ah0, Bh0) ----
        RD_A(0, cur);
        RD_B(0, cur);
        if (tt + 1 < 48) STAGE(tt + 1, 1, 1);   // Bh1(t+1) -> buf^1
        LGK8();
        BAR8();
        LGK0();
        MM16(acc0);
        BAR8();
        // ---- ph2: Q10 (Ah1; Bh0 reused from regs) ----
        RD_A(1, cur);
        if (tt + 1 < 48) STAGE(tt + 1, 0, 0);   // Ah0(t+1) -> buf^1
        BAR8();
        LGK0();
        MM16(acc1);
        BAR8();
        // ---- ph3: Q11 (Bh1; Ah1 reused) ----
        RD_B(1, cur);
        if (tt + 2 < 48) STAGE(tt + 2, 1, 0);   // Bh0(t+2) -> buf (Bh0 dead @ph2)
        BAR8();
        LGK0();
        MM16(acc2);
        BAR8();
        // ---- ph4: Q01 (Ah0 re-read; Bh1 reused) ----
        RD_A(0, cur);
        if (tt + 2 < 48) STAGE(tt + 2, 0, 1);   // Ah1(t+2) -> buf (Ah1 dead @ph3)
        BAR8();
        LGK0();
        MM16(acc3);
        if (tt < 46) { VMW(4); } else { VMW(0); }  // tile t+1 halves landed
        BAR8();
    }

    // ---- epilogue; C/D frag layout: col = lane&15, row = quad*4 + reg ----
    float bs[2][2];
    #pragma unroll
    for (int qn = 0; qn < 2; ++qn)
        #pragma unroll
        for (int ni = 0; ni < 2; ++ni)
            bs[qn][ni] = bias[n0 + qn * 128 + wc * 32 + ni * 16 + lrow];
    float* ofb = of + (size_t)b * (C_LEN * D_DIM);
    #pragma unroll
    for (int mi = 0; mi < 4; ++mi) {
        #pragma unroll
        for (int ni = 0; ni < 2; ++ni) {
            #pragma unroll
            for (int e = 0; e < 4; ++e) {
                const int rA = m0 + wr * 64 + mi * 16 + quad * 4 + e;       // qm=0 rows
                const int rB = rA + 128;                                    // qm=1 rows
                const int cA = n0 + wc * 32 + ni * 16 + lrow;               // qn=0 cols
                const int cB = cA + 128;                                    // qn=1 cols
                ofb[(size_t)rA * D_DIM + cA] = acc0[mi*2+ni][e] + bs[0][ni];
                ofb[(size_t)rB * D_DIM + cA] = acc1[mi*2+ni][e] + bs[0][ni];
                ofb[(size_t)rB * D_DIM + cB] = acc2[mi*2+ni][e] + bs[1][ni];
                ofb[(size_t)rA * D_DIM + cB] = acc3[mi*2+ni][e] + bs[1][ni];
            }
        }
    }
}

// ---------- softmax over Q per (b,c) row; also record rowmax ----------
__global__ void softmax_kernel(const float* __restrict__ S, const float* __restrict__ colterm,
                               u16* __restrict__ P, float* __restrict__ mbuf) {
    int row = blockIdx.x * 4 + (threadIdx.x >> 6);
    int lane = threadIdx.x & 63;
    int b = row >> 11;  // C_LEN = 2048
    const float* sp = S + (size_t)row * Q_LEN;
    const float* cp = colterm + (size_t)b * Q_LEN;
    float v[8];
    float m = -1e30f;
    #pragma unroll
    for (int j = 0; j < 8; ++j) {
        int idx = j * 64 + lane;
        v[j] = sp[idx] + cp[idx];
        m = fmaxf(m, v[j]);
    }
    for (int off = 32; off; off >>= 1) m = fmaxf(m, __shfl_xor(m, off));
    float s = 0.f;
    #pragma unroll
    for (int j = 0; j < 8; ++j) { v[j] = __expf(v[j] - m); s += v[j]; }
    for (int off = 32; off; off >>= 1) s += __shfl_xor(s, off);
    float inv = 1.0f / s;
    u16* pp = P + (size_t)row * Q_LEN;
    #pragma unroll
    for (int j = 0; j < 8; ++j) pp[j * 64 + lane] = f2bf(v[j] * inv);
    if (lane == 0) mbuf[row] = m;
}

// ---------- b_att[b,c] = softmax_c(rowmax + rowterm) ----------
__global__ __launch_bounds__(256) void batt_kernel(const float* __restrict__ mbuf,
                                                   const float* __restrict__ rowterm,
                                                   float* __restrict__ batt) {
    __shared__ float red[8];
    int b = blockIdx.x;
    int tid = threadIdx.x;
    const float* mb = mbuf + (size_t)b * C_LEN;
    const float* rt = rowterm + (size_t)b * C_LEN;
    float v[8];
    float m = -1e30f;
    #pragma unroll
    for (int j = 0; j < 8; ++j) { int idx = j * 256 + tid; v[j] = mb[idx] + rt[idx]; m = fmaxf(m, v[j]); }
    for (int off = 32; off; off >>= 1) m = fmaxf(m, __shfl_xor(m, off));
    int wave = tid >> 6, lane = tid & 63;
    if (lane == 0) red[wave] = m;
    __syncthreads();
    m = fmaxf(fmaxf(red[0], red[1]), fmaxf(red[2], red[3]));
    float s = 0.f;
    #pragma unroll
    for (int j = 0; j < 8; ++j) { v[j] = __expf(v[j] - m); s += v[j]; }
    for (int off = 32; off; off >>= 1) s += __shfl_xor(s, off);
    if (lane == 0) red[4 + wave] = s;
    __syncthreads();
    s = red[4] + red[5] + red[6] + red[7];
    float inv = 1.0f / s;
    float* bb = batt + (size_t)b * C_LEN;
    #pragma unroll
    for (int j = 0; j < 8; ++j) bb[j * 256 + tid] = v[j] * inv;
}

// ---------- q2c[b,d] = sum_c b_att[b,c] * cbf[b,c,d] (chunked + atomic) ----------
__global__ __launch_bounds__(256) void q2c_kernel(const float* __restrict__ batt,
                                                  const u16* __restrict__ cbf,
                                                  float* __restrict__ q2c) {
    int d  = blockIdx.x * 256 + threadIdx.x;
    int b  = blockIdx.y;
    int c0 = blockIdx.z * 256;
    const u16* cb = cbf + ((size_t)b * C_LEN + c0) * D_DIM + d;
    const float* bb = batt + (size_t)b * C_LEN + c0;
    float s = 0.f;
    #pragma unroll 4
    for (int i = 0; i < 256; ++i) s += bb[i] * bf2f(cb[(size_t)i * D_DIM]);
    atomicAdd(&q2c[(size_t)b * D_DIM + d], s);
}

extern "C" void kernel_launch(void* const* d_in, const int* in_sizes, int n_in,
                              void* d_out, int out_size, void* d_ws, size_t ws_size,
                              hipStream_t stream) {
    const float* c   = (const float*)d_in[0];
    const float* q   = (const float*)d_in[1];
    const float* wcq = (const float*)d_in[2];
    // b_cq (d_in[3]), b_c (d_in[5]), b_q (d_in[7]) cancel in both softmaxes — unused.
    const float* w_c = (const float*)d_in[4];
    const float* w_q = (const float*)d_in[6];
    const float* W_l = (const float*)d_in[8];
    const float* b_l = (const float*)d_in[9];
    float* out = (float*)d_out;

    char* ws = (char*)d_ws;
    // Region plan (MiB), lifetime-safe re-use:
    //   [0,32)    cbf                       (prep .. gemm2)
    //   [32,96)   CC interleaved c2q|cc2q   (written gemm<1>, read gemm2)
    //             before gemm<1>: S fp32 @32..64, qwbf @64..72
    //   [96,112)  P bf16 (softmax..gemm<1>), then Wm (wmerge_all..gemm2)
    //   [112,120) qT (prep..gemm<1>), then Wbf compact 4MiB (wmerge_all..gemm2)
    //   [120,...) smalls
    u16*   cbf     = (u16*)ws;
    float* S       = (float*)(ws + 33554432);
    u16*   CC      = (u16*)(ws + 33554432);
    u16*   qwbf    = (u16*)(ws + 67108864);
    u16*   P       = (u16*)(ws + 100663296);
    u16*   Wm      = (u16*)(ws + 100663296);
    u16*   qT      = (u16*)(ws + 117440512);
    u16*   Wbf     = (u16*)(ws + 117440512);
    float* rowterm = (float*)(ws + 125829120);
    float* colterm = (float*)(ws + 125894656);
    float* mbuf    = (float*)(ws + 125911040);
    float* batt    = (float*)(ws + 125976576);
    float* q2c     = (float*)(ws + 126042112);   // total ~120.3 MiB

    prep_kernel<<<dim3(9248), dim3(256), 0, stream>>>(c, q, wcq, w_c, w_q,
                                                      cbf, qwbf, qT, rowterm, colterm, q2c);
    gemm_async<0><<<dim3(512), dim3(256), 0, stream>>>(cbf, nullptr, nullptr, qwbf, nullptr, S, nullptr, nullptr);
    softmax_kernel<<<dim3(4096), dim3(256), 0, stream>>>(S, colterm, P, mbuf);
    batt_kernel<<<dim3(8), dim3(256), 0, stream>>>(mbuf, rowterm, batt);
    q2c_kernel<<<dim3(4, 8, 8), dim3(256), 0, stream>>>(batt, cbf, q2c);
    gemm_async<1><<<dim3(1024), dim3(256), 0, stream>>>(P, cbf, nullptr, qT, nullptr, nullptr, CC, nullptr);
    wmerge_all<<<dim3(1024), dim3(256), 0, stream>>>(W_l, q2c, Wm, Wbf);
    gemm2_8q<<<dim3(256), dim3(512), 0, stream>>>(cbf, CC, Wm, Wbf, out, b_l);
}